// Round 8
// baseline (1868.177 us; speedup 1.0000x reference)
//
#include <hip/hip_runtime.h>
#include <hip/hip_bf16.h>
#include <math.h>

#define OBS 512
#define MSG 2048
#define TAU 576
#define TAUP 640      // padded taus row stride
#define QN 16320
#define X2W 16896
#define INW 3136
#define PIW 2560

typedef short short8v __attribute__((ext_vector_type(8)));
typedef float f32x4 __attribute__((ext_vector_type(4)));
typedef __hip_bfloat16 bf;

__device__ inline unsigned short bfbits(float x) {
  bf h = __float2bfloat16(x);
  return *reinterpret_cast<unsigned short*>(&h);
}

__device__ inline short8v cvt8(float4 a, float4 b) {
  short8v r;
  r[0] = (short)bfbits(a.x); r[1] = (short)bfbits(a.y);
  r[2] = (short)bfbits(a.z); r[3] = (short)bfbits(a.w);
  r[4] = (short)bfbits(b.x); r[5] = (short)bfbits(b.y);
  r[6] = (short)bfbits(b.z); r[7] = (short)bfbits(b.w);
  return r;
}

// ---------------- barrier-free wave-tile GEMM, 2-deep manual pipeline ----------------
// Each wave owns a 32m x 32n tile of C = A(bf16) x W(fp32->bf16 in reg)^T.
// 8 waves/block share one n-strip (W rows deduped via L1/L2). No LDS, no barriers.
// 2 named register sets P0/P1 give a counted-vmcnt pipeline (~12 loads in flight).
// MODE 0: epilogue (bias + optional C fp32 / Cb bf16), grid.z=1.
// MODE 1: partial write to S.C + chunk*(M*ldc), NO bias (consumer sums). grid.z=z.
// DUAL: blockIdx.z&1 picks set (GRU gi/gh), blockIdx.z>>1 = K-chunk.
struct MMSet {
  const bf* A;
  const float* W;
  const float* bias;
  float* C;
  bf* Cb;
  int lda, ldw, ldc, ldcb;
};

template<int MODE, bool DUAL>
__global__ __launch_bounds__(512)
void k_wmm(MMSet s0, MMSet s1, int mTiles, int kSteps)
{
  const int zid = blockIdx.z;
  const MMSet S = (DUAL && (zid & 1)) ? s1 : s0;
  const int chunk = DUAL ? (zid >> 1) : zid;
  const int wid = threadIdx.x >> 6, lane = threadIdx.x & 63;
  const int g = blockIdx.x * 8 + wid;
  const int m_t = g % mTiles, n_t = g / mTiles;
  const int fr = lane & 15, q = lane >> 4;
  const int m0 = m_t * 32, n0 = n_t * 32;
  const size_t k0 = (size_t)chunk * kSteps * 32;

  const bf* A0 = S.A + (size_t)(m0 + fr) * S.lda + k0 + q * 8;
  const bf* A1 = A0 + (size_t)16 * S.lda;
  const float* W0 = S.W + (size_t)(n0 + fr) * S.ldw + k0 + q * 8;
  const float* W1 = W0 + (size_t)16 * S.ldw;

  f32x4 acc00 = {}, acc01 = {}, acc10 = {}, acc11 = {};

  // two named pipeline register sets (no arrays -> no scratch, forced prefetch depth)
  short8v a00, a10, a01, a11;
  float4 w00, w01, w02, w03, w10, w11, w12, w13;

  auto load0 = [&](int t) {
    const int k = t * 32;
    a00 = *(const short8v*)(A0 + k);
    a10 = *(const short8v*)(A1 + k);
    w00 = *(const float4*)(W0 + k);
    w01 = *(const float4*)(W0 + k + 4);
    w02 = *(const float4*)(W1 + k);
    w03 = *(const float4*)(W1 + k + 4);
  };
  auto load1 = [&](int t) {
    const int k = t * 32;
    a01 = *(const short8v*)(A0 + k);
    a11 = *(const short8v*)(A1 + k);
    w10 = *(const float4*)(W0 + k);
    w11 = *(const float4*)(W0 + k + 4);
    w12 = *(const float4*)(W1 + k);
    w13 = *(const float4*)(W1 + k + 4);
  };
  auto comp0 = [&]() {
    short8v b0 = cvt8(w00, w01), b1 = cvt8(w02, w03);
    acc00 = __builtin_amdgcn_mfma_f32_16x16x32_bf16(a00, b0, acc00, 0, 0, 0);
    acc01 = __builtin_amdgcn_mfma_f32_16x16x32_bf16(a00, b1, acc01, 0, 0, 0);
    acc10 = __builtin_amdgcn_mfma_f32_16x16x32_bf16(a10, b0, acc10, 0, 0, 0);
    acc11 = __builtin_amdgcn_mfma_f32_16x16x32_bf16(a10, b1, acc11, 0, 0, 0);
  };
  auto comp1 = [&]() {
    short8v b0 = cvt8(w10, w11), b1 = cvt8(w12, w13);
    acc00 = __builtin_amdgcn_mfma_f32_16x16x32_bf16(a01, b0, acc00, 0, 0, 0);
    acc01 = __builtin_amdgcn_mfma_f32_16x16x32_bf16(a01, b1, acc01, 0, 0, 0);
    acc10 = __builtin_amdgcn_mfma_f32_16x16x32_bf16(a11, b0, acc10, 0, 0, 0);
    acc11 = __builtin_amdgcn_mfma_f32_16x16x32_bf16(a11, b1, acc11, 0, 0, 0);
  };

  load0(0);
  load1(1);
  int t = 0;
  for (; t + 2 < kSteps; t += 2) {   // kSteps even, >=2
    comp0(); load0(t + 2);
    comp1(); load1(t + 3);
  }
  comp0(); comp1();

  const int mb0 = m0 + q * 4;
  const int mb1 = m0 + 16 + q * 4;
  const int nc0 = n0 + fr;
  const int nc1 = n0 + 16 + fr;

  if (MODE == 1) {
    float* P = S.C + (size_t)chunk * mTiles * 32 * S.ldc;
#pragma unroll
    for (int v = 0; v < 4; ++v) {
      P[(size_t)(mb0 + v) * S.ldc + nc0] = acc00[v];
      P[(size_t)(mb0 + v) * S.ldc + nc1] = acc01[v];
      P[(size_t)(mb1 + v) * S.ldc + nc0] = acc10[v];
      P[(size_t)(mb1 + v) * S.ldc + nc1] = acc11[v];
    }
  } else {
    const float bb0 = S.bias[nc0], bb1 = S.bias[nc1];
#pragma unroll
    for (int v = 0; v < 4; ++v) {
      float v00 = acc00[v] + bb0, v01 = acc01[v] + bb1;
      float v10 = acc10[v] + bb0, v11 = acc11[v] + bb1;
      if (S.C) {
        S.C[(size_t)(mb0 + v) * S.ldc + nc0] = v00;
        S.C[(size_t)(mb0 + v) * S.ldc + nc1] = v01;
        S.C[(size_t)(mb1 + v) * S.ldc + nc0] = v10;
        S.C[(size_t)(mb1 + v) * S.ldc + nc1] = v11;
      }
      if (S.Cb) {
        S.Cb[(size_t)(mb0 + v) * S.ldcb + nc0] = __float2bfloat16(v00);
        S.Cb[(size_t)(mb0 + v) * S.ldcb + nc1] = __float2bfloat16(v01);
        S.Cb[(size_t)(mb1 + v) * S.ldcb + nc0] = __float2bfloat16(v10);
        S.Cb[(size_t)(mb1 + v) * S.ldcb + nc1] = __float2bfloat16(v11);
      }
    }
  }
}

// ---------------- partial-sum consumer: out = act(sum_z part + bias) ----------------
__global__ __launch_bounds__(256)
void k_post(const float* __restrict__ part, int z, size_t csz, int N,
            const float* __restrict__ bias, int relu,
            bf* __restrict__ outb, float* __restrict__ outf, int ldout)
{
  size_t idx = (size_t)blockIdx.x * 256 + threadIdx.x;
  int m = (int)(idx / N), n = (int)(idx % N);
  float s = bias[n];
  for (int c = 0; c < z; ++c) s += part[(size_t)c * csz + idx];
  if (relu) s = fmaxf(s, 0.f);
  size_t o = (size_t)m * ldout + n;
  if (outb) outb[o] = __float2bfloat16(s);
  if (outf) outf[o] = s;
}

// ---------------- fused init: hidden split + taus slabs + msg cvt ----------------
__global__ __launch_bounds__(256)
void k_init(const float* __restrict__ in, const float* __restrict__ hid,
            float* __restrict__ h32a, float* __restrict__ h32o, float* __restrict__ h32p,
            bf* __restrict__ hba, bf* __restrict__ hbo,
            bf* __restrict__ hbp, bf* __restrict__ hbp0,
            bf* __restrict__ taus, bf* __restrict__ msgb)
{
  const int bx = blockIdx.x;
  if (bx < 3072) {                       // hidden split: 256x3072
    int idx = bx * 256 + threadIdx.x;
    int b = idx / 3072, c = idx % 3072;
    float v = hid[idx];
    bf hb = __float2bfloat16(v);
    int j = c & 1023;
    if (c < 1024)      { h32a[b * 1024 + j] = v; hba[b * 1024 + j] = hb; }
    else if (c < 2048) { h32o[b * 1024 + j] = v; hbo[b * 1024 + j] = hb; }
    else               { h32p[b * 1024 + j] = v; hbp[b * 1024 + j] = hb; hbp0[b * 1024 + j] = hb; }
  } else if (bx < 3072 + 1920) {         // taus slabs: 3*256*TAUP
    int idx = (bx - 3072) * 256 + threadIdx.x;
    int t = idx / (256 * TAUP);
    int r = (idx / TAUP) % 256;
    int c = idx % TAUP;
    float v = 0.f;
    if (t == 0 && c < TAU)
      v = (c < OBS) ? in[(size_t)r * INW + OBS + c]
                    : in[(size_t)r * INW + 2 * OBS + (c - OBS)];
    taus[idx] = __float2bfloat16(v);
  } else {                               // msg cvt: 256x2048
    int idx = (bx - 3072 - 1920) * 256 + threadIdx.x;
    int b = idx >> 11, c = idx & 2047;
    msgb[idx] = __float2bfloat16(in[(size_t)b * INW + 1088 + c]);
  }
}

// ---------------- GRU elementwise; sums 2 gate partials per side + bias --------------
__global__ __launch_bounds__(256)
void k_gru(const float* __restrict__ giP, const float* __restrict__ ghP,
           const float* __restrict__ bih, const float* __restrict__ bhh,
           const float* __restrict__ hs, int ldsrc,
           float* __restrict__ hd, int lddst, bf* __restrict__ hb)
{
  const size_t CS = (size_t)256 * 3072;
  int idx = blockIdx.x * 256 + threadIdx.x;     // 256*1024
  int b = idx >> 10, j = idx & 1023;
  size_t o = (size_t)b * 3072 + j;
  float ir = giP[o] + giP[CS + o] + bih[j];
  float iz = giP[o + 1024] + giP[CS + o + 1024] + bih[1024 + j];
  float in_ = giP[o + 2048] + giP[CS + o + 2048] + bih[2048 + j];
  float hr = ghP[o] + ghP[CS + o] + bhh[j];
  float hz = ghP[o + 1024] + ghP[CS + o + 1024] + bhh[1024 + j];
  float hn = ghP[o + 2048] + ghP[CS + o + 2048] + bhh[2048 + j];
  float r = 1.f / (1.f + expf(-(ir + hr)));
  float z = 1.f / (1.f + expf(-(iz + hz)));
  float n = tanhf(in_ + r * hn);
  float h = hs[(size_t)b * ldsrc + j];
  float out = (1.f - z) * n + z * h;
  hd[(size_t)b * lddst + j] = out;
  hb[idx] = __float2bfloat16(out);
}

// softmax over 64-wide groups of q (bf16, stride QN), scatter (bf16) into x2
__global__ __launch_bounds__(256)
void k_softmax_scatter(const bf* __restrict__ q, bf* __restrict__ x2)
{
  int wid = blockIdx.x * 4 + (threadIdx.x >> 6);
  int lane = threadIdx.x & 63;
  int b = wid / 255, p = wid % 255;
  float v = __bfloat162float(q[(size_t)b * QN + p * 64 + lane]);
  float m = v;
#pragma unroll
  for (int s = 32; s; s >>= 1) m = fmaxf(m, __shfl_xor(m, s));
  float e = expf(v - m);
  float sum = e;
#pragma unroll
  for (int s = 32; s; s >>= 1) sum += __shfl_xor(sum, s);
  float r = e / sum;
  int flat = p * 16384 + b * 64 + lane;
  int bp = flat / QN;
  int j = flat - bp * QN;
  x2[(size_t)bp * X2W + j] = __float2bfloat16(r);
}

__global__ __launch_bounds__(256)
void k_x2_tail(const bf* __restrict__ taus_t, bf* __restrict__ x2)
{
  int idx = blockIdx.x * 256 + threadIdx.x;   // 256*576
  int b = idx / TAU, c = idx % TAU;
  if (c < 64)
    x2[(size_t)b * X2W + QN + c] = taus_t[(size_t)b * TAUP + OBS + c];
  else
    x2[(size_t)b * X2W + QN + 64 + (c - 64)] = taus_t[(size_t)b * TAUP + (c - 64)];
}

__global__ __launch_bounds__(256)
void k_concat_pi_loop(const bf* __restrict__ taus_t, const bf* __restrict__ msg,
                      bf* __restrict__ piin)
{
  int idx = blockIdx.x * 256 + threadIdx.x;   // 256*2560
  int b = idx / PIW, c = idx % PIW;
  piin[idx] = (c < OBS) ? taus_t[(size_t)b * TAUP + c] : msg[b * MSG + (c - OBS)];
}

__global__ __launch_bounds__(256)
void k_concat_pi_final(const float* __restrict__ in, const float* __restrict__ nm,
                       bf* __restrict__ piin)
{
  int idx = blockIdx.x * 256 + threadIdx.x;
  int b = idx / PIW, c = idx % PIW;
  float v = (c < OBS) ? in[(size_t)b * INW + c] : nm[c - OBS];
  piin[idx] = __float2bfloat16(v);
}

__global__ __launch_bounds__(64)
void k_vv(const bf* __restrict__ taus, const float* __restrict__ w,
          const float* __restrict__ bias, float* __restrict__ vv)
{
  int row = blockIdx.x;        // 0..767
  int lane = threadIdx.x;
  const bf* tr = taus + (size_t)row * TAUP;
  for (int v = 0; v < 8; ++v) {
    float s = 0.f;
    for (int k = lane; k < TAU; k += 64) s += __bfloat162float(tr[k]) * w[v * TAU + k];
#pragma unroll
    for (int d = 32; d; d >>= 1) s += __shfl_xor(s, d);
    if (lane == 0) vv[row * 8 + v] = s + bias[v];
  }
}

__global__ __launch_bounds__(64)
void k_attn(const float* __restrict__ qv, const float* __restrict__ kk,
            const float* __restrict__ vv, float* __restrict__ nm,
            float* __restrict__ out_q)
{
  int b = blockIdx.x;
  int lane = threadIdx.x;
  const float* qb = qv + (size_t)b * 1024;
  float s[3];
#pragma unroll
  for (int t = 0; t < 3; ++t) {
    const float* kb = kk + (size_t)(t * 256 + b) * 1024;
    float acc = 0.f;
    for (int h = lane; h < 1024; h += 64) acc += qb[h] * kb[h];
#pragma unroll
    for (int d = 32; d; d >>= 1) acc += __shfl_xor(acc, d);
    s[t] = acc * (1.f / 32.f);
  }
  float m = fmaxf(s[0], fmaxf(s[1], s[2]));
  float e0 = expf(s[0] - m), e1 = expf(s[1] - m), e2 = expf(s[2] - m);
  float inv = 1.f / (e0 + e1 + e2);
  float a0 = e0 * inv, a1 = e1 * inv, a2 = e2 * inv;
  if (lane < 8) {
    float v = a0 * vv[(0 * 256 + b) * 8 + lane]
            + a1 * vv[(1 * 256 + b) * 8 + lane]
            + a2 * vv[(2 * 256 + b) * 8 + lane];
    nm[b * 8 + lane] = v;
    out_q[b * 72 + lane] = v;
  }
}

__global__ __launch_bounds__(256)
void k_copy_hout(const float* __restrict__ hfa, const float* __restrict__ hfo,
                 float* __restrict__ hout)
{
  int idx = blockIdx.x * 256 + threadIdx.x;   // 256*2048
  int b = idx / 2048, c = idx % 2048;
  float v = (c < 1024) ? hfa[b * 1024 + c] : hfo[b * 1024 + (c - 1024)];
  hout[(size_t)b * 3072 + c] = v;
}

extern "C" void kernel_launch(void* const* d_in, const int* in_sizes, int n_in,
                              void* d_out_v, int out_size, void* d_ws, size_t ws_size,
                              hipStream_t stream)
{
  const float* inputs   = (const float*)d_in[0];
  const float* hidden   = (const float*)d_in[1];
  const float* pi_fc1_w = (const float*)d_in[2];
  const float* pi_fc1_b = (const float*)d_in[3];
  const float* pi_fc2_w = (const float*)d_in[4];
  const float* pi_fc2_b = (const float*)d_in[5];
  const float* fa_fc1_w = (const float*)d_in[6];
  const float* fa_fc1_b = (const float*)d_in[7];
  const float* fa_fc2_w = (const float*)d_in[8];
  const float* fa_fc2_b = (const float*)d_in[9];
  const float* fo_fc1_w = (const float*)d_in[10];
  const float* fo_fc1_b = (const float*)d_in[11];
  const float* fo_fc2_w = (const float*)d_in[12];
  const float* fo_fc2_b = (const float*)d_in[13];
  const float* am_qs_w  = (const float*)d_in[14];
  const float* am_qs_b  = (const float*)d_in[15];
  const float* am_ks_w  = (const float*)d_in[16];
  const float* am_ks_b  = (const float*)d_in[17];
  const float* am_vs_w  = (const float*)d_in[18];
  const float* am_vs_b  = (const float*)d_in[19];
  const float* pi_wih   = (const float*)d_in[20];
  const float* pi_bih   = (const float*)d_in[21];
  const float* pi_whh   = (const float*)d_in[22];
  const float* pi_bhh   = (const float*)d_in[23];
  const float* fa_wih   = (const float*)d_in[24];
  const float* fa_bih   = (const float*)d_in[25];
  const float* fa_whh   = (const float*)d_in[26];
  const float* fa_bhh   = (const float*)d_in[27];
  const float* fo_wih   = (const float*)d_in[28];
  const float* fo_bih   = (const float*)d_in[29];
  const float* fo_whh   = (const float*)d_in[30];
  const float* fo_bhh   = (const float*)d_in[31];

  float* out = (float*)d_out_v;
  char* p = (char*)d_ws;
  auto alloc = [&](size_t bytes) { void* r = p; p += (bytes + 255) & ~(size_t)255; return r; };

  // bf16 activations
  bf* HFAB = (bf*)alloc((size_t)256 * 1024 * 2);
  bf* HFOB = (bf*)alloc((size_t)256 * 1024 * 2);
  bf* HPIB = (bf*)alloc((size_t)256 * 1024 * 2);
  bf* HPI0B = (bf*)alloc((size_t)256 * 1024 * 2);
  bf* XBUFB = (bf*)alloc((size_t)256 * 1024 * 2);
  bf* TAUSB = (bf*)alloc((size_t)3 * 256 * TAUP * 2);
  bf* X2B  = (bf*)alloc((size_t)256 * X2W * 2);
  bf* PIINB = (bf*)alloc((size_t)256 * PIW * 2);
  bf* MSGB = (bf*)alloc((size_t)256 * MSG * 2);
  bf* QBUFB = (bf*)alloc((size_t)256 * QN * 2);
  // fp32 state
  float* HFA32 = (float*)alloc((size_t)256 * 1024 * 4);
  float* HFO32 = (float*)alloc((size_t)256 * 1024 * 4);
  float* HPI32 = (float*)alloc((size_t)256 * 1024 * 4);
  float* QV = (float*)alloc((size_t)256 * 1024 * 4);
  float* KK = (float*)alloc((size_t)768 * 1024 * 4);
  float* VV = (float*)alloc((size_t)768 * 8 * 4);
  float* NM = (float*)alloc((size_t)2048 * 4);
  // partial scratch
  float* PA  = (float*)alloc((size_t)12 * 256 * 1024 * 4);   // shared, max z=12 (am_ks: 3*768K fits)
  float* GIp = (float*)alloc((size_t)2 * 256 * 3072 * 4);
  float* GHp = (float*)alloc((size_t)2 * 256 * 3072 * 4);

  auto mset = [&](const bf* A, int lda, const float* W, int ldw, const float* bias,
                  float* C, int ldc, bf* Cb, int ldcb) {
    MMSet s; s.A = A; s.W = W; s.bias = bias; s.C = C; s.Cb = Cb;
    s.lda = lda; s.ldw = ldw; s.ldc = ldc; s.ldcb = ldcb; return s;
  };
  // partial GEMM: writes [z][M][N] into base (no bias)
  auto wpart = [&](const bf* A, int lda, const float* W, int ldw,
                   float* base, int M, int N, int K, int z) {
    MMSet s = mset(A, lda, W, ldw, nullptr, base, N, nullptr, 0);
    int mt = M / 32;
    dim3 g((mt * (N / 32)) / 8, 1, z);
    k_wmm<1, false><<<g, 512, 0, stream>>>(s, s, mt, K / (32 * z));
  };
  // direct-epilogue GEMM (no split)
  auto wepi = [&](MMSet s, int M, int N, int K) {
    int mt = M / 32;
    dim3 g((mt * (N / 32)) / 8, 1, 1);
    k_wmm<0, false><<<g, 512, 0, stream>>>(s, s, mt, K / 32);
  };
  // dual gate pair, z-split 2 per set
  auto wgates = [&](const bf* A1p, const float* wih, const bf* A2p, const float* whh) {
    MMSet a = mset(A1p, 1024, wih, 1024, nullptr, GIp, 3072, nullptr, 0);
    MMSet b = mset(A2p, 1024, whh, 1024, nullptr, GHp, 3072, nullptr, 0);
    dim3 g(96, 1, 4);
    k_wmm<1, true><<<g, 512, 0, stream>>>(a, b, 8, 16);   // K=1024, z=2 -> 16 steps
  };
  auto post = [&](float* part, int z, int M, int N, const float* bias, int relu,
                  bf* outb, float* outf, int ldout) {
    k_post<<<(M * N) / 256, 256, 0, stream>>>(part, z, (size_t)M * N, N, bias, relu,
                                              outb, outf, ldout);
  };
  auto gru = [&](const float* bih, const float* bhh, const float* hs, int ldsrc,
                 float* hd, int lddst, bf* hb) {
    k_gru<<<1024, 256, 0, stream>>>(GIp, GHp, bih, bhh, hs, ldsrc, hd, lddst, hb);
  };

  k_init<<<3072 + 1920 + 2048, 256, 0, stream>>>(inputs, hidden,
      HFA32, HFO32, HPI32, HFAB, HFOB, HPIB, HPI0B, TAUSB, MSGB);

  for (int t = 0; t < 2; ++t) {
    bf* taus_t = TAUSB + (size_t)t * 256 * TAUP;
    bf* taus_n = TAUSB + (size_t)(t + 1) * 256 * TAUP;
    // fa branch
    wpart(taus_t, TAUP, fa_fc1_w, 512, PA, 256, 1024, 512, 4);
    post(PA, 4, 256, 1024, fa_fc1_b, 1, XBUFB, nullptr, 1024);
    wgates(XBUFB, fa_wih, HFAB, fa_whh);
    gru(fa_bih, fa_bhh, HFA32, 1024, HFA32, 1024, HFAB);
    wepi(mset(HFAB, 1024, fa_fc2_w, 1024, fa_fc2_b, nullptr, 0, QBUFB, QN), 256, QN, 1024);
    // x2 = [scrambled softmax | a | o]
    k_x2_tail<<<576, 256, 0, stream>>>(taus_t, X2B);
    k_softmax_scatter<<<16320, 256, 0, stream>>>(QBUFB, X2B);
    // fo branch
    wpart(X2B, X2W, fo_fc1_w, X2W, PA, 256, 1024, X2W, 12);
    post(PA, 12, 256, 1024, fo_fc1_b, 1, XBUFB, nullptr, 1024);
    wgates(XBUFB, fo_wih, HFOB, fo_whh);
    gru(fo_bih, fo_bhh, HFO32, 1024, HFO32, 1024, HFOB);
    wpart(HFOB, 1024, fo_fc2_w, 1024, PA, 256, 512, 1024, 4);
    post(PA, 4, 256, 512, fo_fc2_b, 0, taus_n, nullptr, TAUP);
    // pi branch
    k_concat_pi_loop<<<2560, 256, 0, stream>>>(taus_t, MSGB, PIINB);
    wpart(PIINB, PIW, pi_fc1_w, PIW, PA, 256, 1024, PIW, 8);
    post(PA, 8, 256, 1024, pi_fc1_b, 1, XBUFB, nullptr, 1024);
    wgates(XBUFB, pi_wih, HPIB, pi_whh);
    gru(pi_bih, pi_bhh, HPI32, 1024, HPI32, 1024, HPIB);
    wpart(HPIB, 1024, pi_fc2_w, 1024, PA, 256, 64, 1024, 8);
    post(PA, 8, 256, 64, pi_fc2_b, 0, taus_n + OBS, nullptr, TAUP);
  }

  // attention
  wpart(MSGB, MSG, am_qs_w, MSG, PA, 256, 1024, 2048, 4);
  post(PA, 4, 256, 1024, am_qs_b, 0, nullptr, QV, 1024);
  wpart(TAUSB, TAUP, am_ks_w, TAU, PA, 768, 1024, TAU, 3);
  post(PA, 3, 768, 1024, am_ks_b, 0, nullptr, KK, 1024);
  k_vv<<<768, 64, 0, stream>>>(TAUSB, am_vs_w, am_vs_b, VV);
  k_attn<<<256, 64, 0, stream>>>(QV, KK, VV, NM, out);

  // final pi with original h_pi0
  k_concat_pi_final<<<2560, 256, 0, stream>>>(inputs, NM, PIINB);
  wpart(PIINB, PIW, pi_fc1_w, PIW, PA, 256, 1024, PIW, 8);
  post(PA, 8, 256, 1024, pi_fc1_b, 1, XBUFB, nullptr, 1024);
  wgates(XBUFB, pi_wih, HPI0B, pi_whh);
  gru(pi_bih, pi_bhh, hidden + 2048, 3072, out + 256 * 72 + 2048, 3072, HPIB);
  wpart(HPIB, 1024, pi_fc2_w, 1024, PA, 256, 64, 1024, 8);
  post(PA, 8, 256, 64, pi_fc2_b, 0, nullptr, out + 8, 72);
  k_copy_hout<<<2048, 256, 0, stream>>>(HFA32, HFO32, out + 256 * 72);
  (void)in_sizes; (void)n_in; (void)out_size; (void)ws_size;
}

// Round 9
// 636.974 us; speedup vs baseline: 2.9329x; 2.9329x over previous
//
#include <hip/hip_runtime.h>
#include <hip/hip_bf16.h>
#include <math.h>

#define OBS 512
#define MSG 2048
#define TAU 576
#define TAUP 640      // padded taus row stride
#define QN 16320
#define X2W 16896
#define INW 3136
#define PIW 2560

typedef short short8v __attribute__((ext_vector_type(8)));
typedef float f32x4 __attribute__((ext_vector_type(4)));
typedef __hip_bfloat16 bf;

__device__ inline unsigned short bfbits(float x) {
  bf h = __float2bfloat16(x);
  return *reinterpret_cast<unsigned short*>(&h);
}

__device__ inline ushort4 cvtf4(float4 v) {
  ushort4 r;
  r.x = bfbits(v.x); r.y = bfbits(v.y); r.z = bfbits(v.z); r.w = bfbits(v.w);
  return r;
}

__device__ inline void gload16(const void* g, void* l) {
  __builtin_amdgcn_global_load_lds((__attribute__((address_space(1))) void*)(g),
                                   (__attribute__((address_space(3))) void*)(l), 16, 0, 0);
}

// ---------------- bf16-MFMA NT matmul, BM=BN=64, BK=64, dbuf, 4 waves ----------------
// C[m,n] = act(sum_k A[m,k]*W[n,k] + bias[n]); A bf16 (lda), W fp32 (ldw, cvt in-reg).
// A: global_load_lds (pre-swizzled source, linear LDS). W: coalesced float4 reg-stage
// (issue next-tile early, cvt+swizzled ds_write late), XOR-swizzled LDS rows.
// Small tile -> 4-6 blocks/CU; co-resident blocks hide each other's barrier drains.
// ATOMIC: blockIdx.z = K-chunk, fp32 atomicAdd into bias-prefilled C (no epilogue).
// DUAL: blockIdx.z picks set (GRU gi/gh pair).
struct MMSet {
  const bf* A;
  const float* W;
  const float* bias;
  float* C;
  bf* Cb;
  int lda, ldw, ldc, ldcb;
};

template<int ACT, bool ATOMIC, bool DUAL>
__global__ __launch_bounds__(256)
void k_mm(MMSet s0, MMSet s1, int kSteps)
{
  __shared__ bf As[2][64 * 64];
  __shared__ bf Bs[2][64 * 64];
  const MMSet S = (DUAL && blockIdx.z) ? s1 : s0;
  const int tid = threadIdx.x;
  const int lane = tid & 63;
  const int wid = tid >> 6;
  const int m0 = blockIdx.y * 64;
  const int n0 = blockIdx.x * 64;
  const size_t k0 = ATOMIC ? (size_t)blockIdx.z * kSteps * 64 : 0;

  const bf* Ab = S.A + (size_t)m0 * S.lda + k0;
  const float* Bb = S.W + (size_t)n0 * S.ldw + k0;

  // A staging: 512 chunks of 16B (8 bf16), 2 rounds. LDS linear; global col swizzled.
  int arow[2], acol[2], adst[2];
#pragma unroll
  for (int r = 0; r < 2; ++r) {
    int chunk = r * 256 + tid;
    arow[r] = chunk >> 3;
    acol[r] = ((chunk & 7) ^ (arow[r] & 7)) * 8;
    adst[r] = chunk * 8;
  }
  // W staging: 1024 float4 chunks, 4 rounds; dest = swizzled 8B (4 bf16) slot.
  int brow[4], bcol[4], bdst[4];
#pragma unroll
  for (int r = 0; r < 4; ++r) {
    int c = r * 256 + tid;
    brow[r] = c >> 4;
    int g = (c & 15) >> 1, half = c & 1;
    bcol[r] = (c & 15) * 4;
    bdst[r] = brow[r] * 64 + ((g ^ (brow[r] & 7)) << 3) + half * 4;
  }

  const int wr = wid >> 1, wc = wid & 1;   // wave tile 32m x 32n
  const int fr = lane & 15, q = lane >> 4;
  const int xm = fr & 7;

  f32x4 acc00 = {}, acc01 = {}, acc10 = {}, acc11 = {};
  float4 w0, w1, w2, w3;

  auto stageA = [&](int buf, int kt) {
#pragma unroll
    for (int r = 0; r < 2; ++r)
      gload16(Ab + (size_t)arow[r] * S.lda + kt + acol[r], &As[buf][adst[r]]);
  };
  auto loadB = [&](int kt) {
    w0 = *(const float4*)(Bb + (size_t)brow[0] * S.ldw + kt + bcol[0]);
    w1 = *(const float4*)(Bb + (size_t)brow[1] * S.ldw + kt + bcol[1]);
    w2 = *(const float4*)(Bb + (size_t)brow[2] * S.ldw + kt + bcol[2]);
    w3 = *(const float4*)(Bb + (size_t)brow[3] * S.ldw + kt + bcol[3]);
  };
  auto writeB = [&](int buf) {
    *(ushort4*)&Bs[buf][bdst[0]] = cvtf4(w0);
    *(ushort4*)&Bs[buf][bdst[1]] = cvtf4(w1);
    *(ushort4*)&Bs[buf][bdst[2]] = cvtf4(w2);
    *(ushort4*)&Bs[buf][bdst[3]] = cvtf4(w3);
  };

  stageA(0, 0);
  loadB(0);
  writeB(0);
  __syncthreads();

  for (int t = 0; t < kSteps; ++t) {
    const int buf = t & 1;
    if (t + 1 < kSteps) {
      stageA(buf ^ 1, (t + 1) * 64);   // async -> LDS
      loadB((t + 1) * 64);             // issue-early to regs
    }
    const bf* Ac = As[buf];
    const bf* Bc = Bs[buf];
#pragma unroll
    for (int ks = 0; ks < 2; ++ks) {
      const int cc = ks * 4 + q;
      const int co = ((cc ^ xm) << 3);
      short8v a0 = *(const short8v*)&Ac[(wr * 32 +  0 + fr) * 64 + co];
      short8v a1 = *(const short8v*)&Ac[(wr * 32 + 16 + fr) * 64 + co];
      short8v b0 = *(const short8v*)&Bc[(wc * 32 +  0 + fr) * 64 + co];
      short8v b1 = *(const short8v*)&Bc[(wc * 32 + 16 + fr) * 64 + co];
      acc00 = __builtin_amdgcn_mfma_f32_16x16x32_bf16(a0, b0, acc00, 0, 0, 0);
      acc01 = __builtin_amdgcn_mfma_f32_16x16x32_bf16(a0, b1, acc01, 0, 0, 0);
      acc10 = __builtin_amdgcn_mfma_f32_16x16x32_bf16(a1, b0, acc10, 0, 0, 0);
      acc11 = __builtin_amdgcn_mfma_f32_16x16x32_bf16(a1, b1, acc11, 0, 0, 0);
    }
    if (t + 1 < kSteps) writeB(buf ^ 1);   // cvt + ds_write late
    __syncthreads();
  }

  const int mb0 = m0 + wr * 32 + q * 4;
  const int mb1 = mb0 + 16;
  const int nc0 = n0 + wc * 32 + fr;
  const int nc1 = nc0 + 16;
  if (ATOMIC) {
#pragma unroll
    for (int v = 0; v < 4; ++v) {
      atomicAdd(&S.C[(size_t)(mb0 + v) * S.ldc + nc0], acc00[v]);
      atomicAdd(&S.C[(size_t)(mb0 + v) * S.ldc + nc1], acc01[v]);
      atomicAdd(&S.C[(size_t)(mb1 + v) * S.ldc + nc0], acc10[v]);
      atomicAdd(&S.C[(size_t)(mb1 + v) * S.ldc + nc1], acc11[v]);
    }
  } else {
    const float bb0 = S.bias[nc0], bb1 = S.bias[nc1];
#pragma unroll
    for (int v = 0; v < 4; ++v) {
      float v00 = acc00[v] + bb0, v01 = acc01[v] + bb1;
      float v10 = acc10[v] + bb0, v11 = acc11[v] + bb1;
      if (ACT) { v00 = fmaxf(v00, 0.f); v01 = fmaxf(v01, 0.f);
                 v10 = fmaxf(v10, 0.f); v11 = fmaxf(v11, 0.f); }
      if (S.C) {
        S.C[(size_t)(mb0 + v) * S.ldc + nc0] = v00;
        S.C[(size_t)(mb0 + v) * S.ldc + nc1] = v01;
        S.C[(size_t)(mb1 + v) * S.ldc + nc0] = v10;
        S.C[(size_t)(mb1 + v) * S.ldc + nc1] = v11;
      }
      if (S.Cb) {
        S.Cb[(size_t)(mb0 + v) * S.ldcb + nc0] = __float2bfloat16(v00);
        S.Cb[(size_t)(mb0 + v) * S.ldcb + nc1] = __float2bfloat16(v01);
        S.Cb[(size_t)(mb1 + v) * S.ldcb + nc0] = __float2bfloat16(v10);
        S.Cb[(size_t)(mb1 + v) * S.ldcb + nc1] = __float2bfloat16(v11);
      }
    }
  }
}

// -------- fused init: hidden split + taus slabs + msg cvt + bias prefills ------------
__global__ __launch_bounds__(256)
void k_init(const float* __restrict__ in, const float* __restrict__ hid,
            float* __restrict__ h32a, float* __restrict__ h32o, float* __restrict__ h32p,
            bf* __restrict__ hba, bf* __restrict__ hbo,
            bf* __restrict__ hbp, bf* __restrict__ hbp0,
            bf* __restrict__ taus, bf* __restrict__ msgb,
            const float* __restrict__ fo1b, float* __restrict__ xf0, float* __restrict__ xf1,
            const float* __restrict__ pi1b, float* __restrict__ xp0,
            float* __restrict__ xp1, float* __restrict__ xp2)
{
  const int bx = blockIdx.x;
  if (bx < 3072) {                       // hidden split: 256x3072
    int idx = bx * 256 + threadIdx.x;
    int b = idx / 3072, c = idx % 3072;
    float v = hid[idx];
    bf hb = __float2bfloat16(v);
    int j = c & 1023;
    if (c < 1024)      { h32a[b * 1024 + j] = v; hba[b * 1024 + j] = hb; }
    else if (c < 2048) { h32o[b * 1024 + j] = v; hbo[b * 1024 + j] = hb; }
    else               { h32p[b * 1024 + j] = v; hbp[b * 1024 + j] = hb; hbp0[b * 1024 + j] = hb; }
  } else if (bx < 3072 + 1920) {         // taus slabs: 3*256*TAUP
    int idx = (bx - 3072) * 256 + threadIdx.x;
    int t = idx / (256 * TAUP);
    int r = (idx / TAUP) % 256;
    int c = idx % TAUP;
    float v = 0.f;
    if (t == 0 && c < TAU)
      v = (c < OBS) ? in[(size_t)r * INW + OBS + c]
                    : in[(size_t)r * INW + 2 * OBS + (c - OBS)];
    taus[idx] = __float2bfloat16(v);
  } else if (bx < 3072 + 1920 + 2048) {  // msg cvt: 256x2048
    int idx = (bx - 3072 - 1920) * 256 + threadIdx.x;
    int b = idx >> 11, c = idx & 2047;
    msgb[idx] = __float2bfloat16(in[(size_t)b * INW + 1088 + c]);
  } else if (bx < 3072 + 1920 + 2048 + 1024) {  // fo_fc1 bias prefill (both iters)
    int idx = (bx - 3072 - 1920 - 2048) * 256 + threadIdx.x;
    float v = fo1b[idx & 1023];
    xf0[idx] = v; xf1[idx] = v;
  } else {                               // pi_fc1 bias prefill (3 calls)
    int idx = (bx - 3072 - 1920 - 2048 - 1024) * 256 + threadIdx.x;
    float v = pi1b[idx & 1023];
    xp0[idx] = v; xp1[idx] = v; xp2[idx] = v;
  }
}

// ---------------- GRU elementwise (fp32 math, dual fp32+bf16 out) ----------------
__global__ __launch_bounds__(256)
void k_gru(const float* __restrict__ gi, const float* __restrict__ gh,
           const float* __restrict__ hs, int ldsrc,
           float* __restrict__ hd, int lddst, bf* __restrict__ hb)
{
  int idx = blockIdx.x * 256 + threadIdx.x;     // 256*1024
  int b = idx >> 10, j = idx & 1023;
  float ir = gi[b * 3072 + j];
  float iz = gi[b * 3072 + 1024 + j];
  float in_ = gi[b * 3072 + 2048 + j];
  float hr = gh[b * 3072 + j];
  float hz = gh[b * 3072 + 1024 + j];
  float hn = gh[b * 3072 + 2048 + j];
  float r = 1.f / (1.f + expf(-(ir + hr)));
  float z = 1.f / (1.f + expf(-(iz + hz)));
  float n = tanhf(in_ + r * hn);
  float h = hs[(size_t)b * ldsrc + j];
  float o = (1.f - z) * n + z * h;
  hd[(size_t)b * lddst + j] = o;
  hb[idx] = __float2bfloat16(o);
}

// softmax over 64-wide groups of q (bf16, stride QN), scatter (bf16) into x2
__global__ __launch_bounds__(256)
void k_softmax_scatter(const bf* __restrict__ q, bf* __restrict__ x2)
{
  int wid = blockIdx.x * 4 + (threadIdx.x >> 6);
  int lane = threadIdx.x & 63;
  int b = wid / 255, p = wid % 255;
  float v = __bfloat162float(q[(size_t)b * QN + p * 64 + lane]);
  float m = v;
#pragma unroll
  for (int s = 32; s; s >>= 1) m = fmaxf(m, __shfl_xor(m, s));
  float e = expf(v - m);
  float sum = e;
#pragma unroll
  for (int s = 32; s; s >>= 1) sum += __shfl_xor(sum, s);
  float r = e / sum;
  int flat = p * 16384 + b * 64 + lane;
  int bp = flat / QN;
  int j = flat - bp * QN;
  x2[(size_t)bp * X2W + j] = __float2bfloat16(r);
}

__global__ __launch_bounds__(256)
void k_x2_tail(const bf* __restrict__ taus_t, bf* __restrict__ x2)
{
  int idx = blockIdx.x * 256 + threadIdx.x;   // 256*576
  int b = idx / TAU, c = idx % TAU;
  if (c < 64)
    x2[(size_t)b * X2W + QN + c] = taus_t[(size_t)b * TAUP + OBS + c];
  else
    x2[(size_t)b * X2W + QN + 64 + (c - 64)] = taus_t[(size_t)b * TAUP + (c - 64)];
}

__global__ __launch_bounds__(256)
void k_concat_pi_loop(const bf* __restrict__ taus_t, const bf* __restrict__ msg,
                      bf* __restrict__ piin)
{
  int idx = blockIdx.x * 256 + threadIdx.x;   // 256*2560
  int b = idx / PIW, c = idx % PIW;
  piin[idx] = (c < OBS) ? taus_t[(size_t)b * TAUP + c] : msg[b * MSG + (c - OBS)];
}

__global__ __launch_bounds__(256)
void k_concat_pi_final(const float* __restrict__ in, const float* __restrict__ nm,
                       bf* __restrict__ piin)
{
  int idx = blockIdx.x * 256 + threadIdx.x;
  int b = idx / PIW, c = idx % PIW;
  float v = (c < OBS) ? in[(size_t)b * INW + c] : nm[c - OBS];
  piin[idx] = __float2bfloat16(v);
}

__global__ __launch_bounds__(256)
void k_relu_cvt(const float* __restrict__ s, bf* __restrict__ d)
{
  int idx = blockIdx.x * 256 + threadIdx.x;
  d[idx] = __float2bfloat16(fmaxf(s[idx], 0.f));
}

__global__ __launch_bounds__(64)
void k_vv(const bf* __restrict__ taus, const float* __restrict__ w,
          const float* __restrict__ bias, float* __restrict__ vv)
{
  int row = blockIdx.x;        // 0..767
  int lane = threadIdx.x;
  const bf* tr = taus + (size_t)row * TAUP;
  for (int v = 0; v < 8; ++v) {
    float s = 0.f;
    for (int k = lane; k < TAU; k += 64) s += __bfloat162float(tr[k]) * w[v * TAU + k];
#pragma unroll
    for (int d = 32; d; d >>= 1) s += __shfl_xor(s, d);
    if (lane == 0) vv[row * 8 + v] = s + bias[v];
  }
}

__global__ __launch_bounds__(64)
void k_attn(const float* __restrict__ qv, const float* __restrict__ kk,
            const float* __restrict__ vv, float* __restrict__ nm,
            float* __restrict__ out_q)
{
  int b = blockIdx.x;
  int lane = threadIdx.x;
  const float* qb = qv + (size_t)b * 1024;
  float s[3];
#pragma unroll
  for (int t = 0; t < 3; ++t) {
    const float* kb = kk + (size_t)(t * 256 + b) * 1024;
    float acc = 0.f;
    for (int h = lane; h < 1024; h += 64) acc += qb[h] * kb[h];
#pragma unroll
    for (int d = 32; d; d >>= 1) acc += __shfl_xor(acc, d);
    s[t] = acc * (1.f / 32.f);
  }
  float m = fmaxf(s[0], fmaxf(s[1], s[2]));
  float e0 = expf(s[0] - m), e1 = expf(s[1] - m), e2 = expf(s[2] - m);
  float inv = 1.f / (e0 + e1 + e2);
  float a0 = e0 * inv, a1 = e1 * inv, a2 = e2 * inv;
  if (lane < 8) {
    float v = a0 * vv[(0 * 256 + b) * 8 + lane]
            + a1 * vv[(1 * 256 + b) * 8 + lane]
            + a2 * vv[(2 * 256 + b) * 8 + lane];
    nm[b * 8 + lane] = v;
    out_q[b * 72 + lane] = v;
  }
}

__global__ __launch_bounds__(256)
void k_copy_hout(const float* __restrict__ hfa, const float* __restrict__ hfo,
                 float* __restrict__ hout)
{
  int idx = blockIdx.x * 256 + threadIdx.x;   // 256*2048
  int b = idx / 2048, c = idx % 2048;
  float v = (c < 1024) ? hfa[b * 1024 + c] : hfo[b * 1024 + (c - 1024)];
  hout[(size_t)b * 3072 + c] = v;
}

extern "C" void kernel_launch(void* const* d_in, const int* in_sizes, int n_in,
                              void* d_out_v, int out_size, void* d_ws, size_t ws_size,
                              hipStream_t stream)
{
  const float* inputs   = (const float*)d_in[0];
  const float* hidden   = (const float*)d_in[1];
  const float* pi_fc1_w = (const float*)d_in[2];
  const float* pi_fc1_b = (const float*)d_in[3];
  const float* pi_fc2_w = (const float*)d_in[4];
  const float* pi_fc2_b = (const float*)d_in[5];
  const float* fa_fc1_w = (const float*)d_in[6];
  const float* fa_fc1_b = (const float*)d_in[7];
  const float* fa_fc2_w = (const float*)d_in[8];
  const float* fa_fc2_b = (const float*)d_in[9];
  const float* fo_fc1_w = (const float*)d_in[10];
  const float* fo_fc1_b = (const float*)d_in[11];
  const float* fo_fc2_w = (const float*)d_in[12];
  const float* fo_fc2_b = (const float*)d_in[13];
  const float* am_qs_w  = (const float*)d_in[14];
  const float* am_qs_b  = (const float*)d_in[15];
  const float* am_ks_w  = (const float*)d_in[16];
  const float* am_ks_b  = (const float*)d_in[17];
  const float* am_vs_w  = (const float*)d_in[18];
  const float* am_vs_b  = (const float*)d_in[19];
  const float* pi_wih   = (const float*)d_in[20];
  const float* pi_bih   = (const float*)d_in[21];
  const float* pi_whh   = (const float*)d_in[22];
  const float* pi_bhh   = (const float*)d_in[23];
  const float* fa_wih   = (const float*)d_in[24];
  const float* fa_bih   = (const float*)d_in[25];
  const float* fa_whh   = (const float*)d_in[26];
  const float* fa_bhh   = (const float*)d_in[27];
  const float* fo_wih   = (const float*)d_in[28];
  const float* fo_bih   = (const float*)d_in[29];
  const float* fo_whh   = (const float*)d_in[30];
  const float* fo_bhh   = (const float*)d_in[31];

  float* out = (float*)d_out_v;
  char* p = (char*)d_ws;
  auto alloc = [&](size_t bytes) { void* r = p; p += (bytes + 255) & ~(size_t)255; return r; };

  // bf16 activations
  bf* HFAB = (bf*)alloc((size_t)256 * 1024 * 2);
  bf* HFOB = (bf*)alloc((size_t)256 * 1024 * 2);
  bf* HPIB = (bf*)alloc((size_t)256 * 1024 * 2);
  bf* HPI0B = (bf*)alloc((size_t)256 * 1024 * 2);
  bf* XBUFB = (bf*)alloc((size_t)256 * 1024 * 2);
  bf* TAUSB = (bf*)alloc((size_t)3 * 256 * TAUP * 2);
  bf* X2B  = (bf*)alloc((size_t)256 * X2W * 2);
  bf* PIINB = (bf*)alloc((size_t)256 * PIW * 2);
  bf* MSGB = (bf*)alloc((size_t)256 * MSG * 2);
  bf* QBUFB = (bf*)alloc((size_t)256 * QN * 2);
  // fp32
  float* HFA32 = (float*)alloc((size_t)256 * 1024 * 4);
  float* HFO32 = (float*)alloc((size_t)256 * 1024 * 4);
  float* HPI32 = (float*)alloc((size_t)256 * 1024 * 4);
  float* XF32A = (float*)alloc((size_t)256 * 1024 * 4);
  float* XF32B = (float*)alloc((size_t)256 * 1024 * 4);
  float* XP32A = (float*)alloc((size_t)256 * 1024 * 4);
  float* XP32B = (float*)alloc((size_t)256 * 1024 * 4);
  float* XP32C = (float*)alloc((size_t)256 * 1024 * 4);
  float* GI = (float*)alloc((size_t)256 * 3072 * 4);
  float* GH = (float*)alloc((size_t)256 * 3072 * 4);
  float* QV = (float*)alloc((size_t)256 * 1024 * 4);
  float* KK = (float*)alloc((size_t)768 * 1024 * 4);
  float* VV = (float*)alloc((size_t)768 * 8 * 4);
  float* NM = (float*)alloc((size_t)2048 * 4);

  auto mset = [&](const bf* A, int lda, const float* W, int ldw, const float* bias,
                  float* C, int ldc, bf* Cb, int ldcb) {
    MMSet s; s.A = A; s.W = W; s.bias = bias; s.C = C; s.Cb = Cb;
    s.lda = lda; s.ldw = ldw; s.ldc = ldc; s.ldcb = ldcb; return s;
  };
  auto mm = [&](MMSet a, int M, int N, int K, int act) {
    dim3 g(N / 64, M / 64, 1);
    if (act) k_mm<1, false, false><<<g, 256, 0, stream>>>(a, a, K / 64);
    else     k_mm<0, false, false><<<g, 256, 0, stream>>>(a, a, K / 64);
  };
  auto mmAtomic = [&](const bf* A, int lda, const float* W, int ldw,
                      float* C, int M, int N, int K, int z) {
    MMSet s = mset(A, lda, W, ldw, nullptr, C, N, nullptr, 0);
    dim3 g(N / 64, M / 64, z);
    k_mm<0, true, false><<<g, 256, 0, stream>>>(s, s, K / (64 * z));
  };
  auto mmDual = [&](MMSet a, MMSet b, int N, int K) {
    dim3 g(N / 64, 4, 2);
    k_mm<0, false, true><<<g, 256, 0, stream>>>(a, b, K / 64);
  };

  k_init<<<3072 + 1920 + 2048 + 1024 + 1024, 256, 0, stream>>>(inputs, hidden,
      HFA32, HFO32, HPI32, HFAB, HFOB, HPIB, HPI0B, TAUSB, MSGB,
      fo_fc1_b, XF32A, XF32B, pi_fc1_b, XP32A, XP32B, XP32C);

  for (int t = 0; t < 2; ++t) {
    bf* taus_t = TAUSB + (size_t)t * 256 * TAUP;
    bf* taus_n = TAUSB + (size_t)(t + 1) * 256 * TAUP;
    float* xf32 = t ? XF32B : XF32A;
    float* xp32 = t ? XP32B : XP32A;
    // fa branch
    mm(mset(taus_t, TAUP, fa_fc1_w, 512, fa_fc1_b, nullptr, 0, XBUFB, 1024), 256, 1024, 512, 1);
    mmDual(mset(XBUFB, 1024, fa_wih, 1024, fa_bih, GI, 3072, nullptr, 0),
           mset(HFAB, 1024, fa_whh, 1024, fa_bhh, GH, 3072, nullptr, 0), 3072, 1024);
    k_gru<<<1024, 256, 0, stream>>>(GI, GH, HFA32, 1024, HFA32, 1024, HFAB);
    mm(mset(HFAB, 1024, fa_fc2_w, 1024, fa_fc2_b, nullptr, 0, QBUFB, QN), 256, QN, 1024, 0);
    // x2 = [scrambled softmax | a | o]
    k_x2_tail<<<576, 256, 0, stream>>>(taus_t, X2B);
    k_softmax_scatter<<<16320, 256, 0, stream>>>(QBUFB, X2B);
    // fo branch: z=12 atomic onto bias-prefilled buffer
    mmAtomic(X2B, X2W, fo_fc1_w, X2W, xf32, 256, 1024, X2W, 12);
    k_relu_cvt<<<1024, 256, 0, stream>>>(xf32, XBUFB);
    mmDual(mset(XBUFB, 1024, fo_wih, 1024, fo_bih, GI, 3072, nullptr, 0),
           mset(HFOB, 1024, fo_whh, 1024, fo_bhh, GH, 3072, nullptr, 0), 3072, 1024);
    k_gru<<<1024, 256, 0, stream>>>(GI, GH, HFO32, 1024, HFO32, 1024, HFOB);
    mm(mset(HFOB, 1024, fo_fc2_w, 1024, fo_fc2_b, nullptr, 0, taus_n, TAUP), 256, 512, 1024, 0);
    // pi branch: z=4 atomic onto bias-prefilled buffer
    k_concat_pi_loop<<<2560, 256, 0, stream>>>(taus_t, MSGB, PIINB);
    mmAtomic(PIINB, PIW, pi_fc1_w, PIW, xp32, 256, 1024, PIW, 4);
    k_relu_cvt<<<1024, 256, 0, stream>>>(xp32, XBUFB);
    mmDual(mset(XBUFB, 1024, pi_wih, 1024, pi_bih, GI, 3072, nullptr, 0),
           mset(HPIB, 1024, pi_whh, 1024, pi_bhh, GH, 3072, nullptr, 0), 3072, 1024);
    k_gru<<<1024, 256, 0, stream>>>(GI, GH, HPI32, 1024, HPI32, 1024, HPIB);
    mm(mset(HPIB, 1024, pi_fc2_w, 1024, pi_fc2_b, nullptr, 0, taus_n + OBS, TAUP), 256, 64, 1024, 0);
  }

  // attention
  mm(mset(MSGB, MSG, am_qs_w, MSG, am_qs_b, QV, 1024, nullptr, 0), 256, 1024, 2048, 0);
  mm(mset(TAUSB, TAUP, am_ks_w, TAU, am_ks_b, KK, 1024, nullptr, 0), 768, 1024, TAU, 0);
  k_vv<<<768, 64, 0, stream>>>(TAUSB, am_vs_w, am_vs_b, VV);
  k_attn<<<256, 64, 0, stream>>>(QV, KK, VV, NM, out);

  // final pi with original h_pi0
  k_concat_pi_final<<<2560, 256, 0, stream>>>(inputs, NM, PIINB);
  mmAtomic(PIINB, PIW, pi_fc1_w, PIW, XP32C, 256, 1024, PIW, 4);
  k_relu_cvt<<<1024, 256, 0, stream>>>(XP32C, XBUFB);
  mmDual(mset(XBUFB, 1024, pi_wih, 1024, pi_bih, GI, 3072, nullptr, 0),
         mset(HPI0B, 1024, pi_whh, 1024, pi_bhh, GH, 3072, nullptr, 0), 3072, 1024);
  k_gru<<<1024, 256, 0, stream>>>(GI, GH, hidden + 2048, 3072,
                                  out + 256 * 72 + 2048, 3072, HPIB);
  mm(mset(HPIB, 1024, pi_fc2_w, 1024, pi_fc2_b, out + 8, 72, nullptr, 0), 256, 64, 1024, 0);
  k_copy_hout<<<2048, 256, 0, stream>>>(HFA32, HFO32, out + 256 * 72);
  (void)in_sizes; (void)n_in; (void)out_size; (void)ws_size;
}

// Round 10
// 617.650 us; speedup vs baseline: 3.0247x; 1.0313x over previous
//
#include <hip/hip_runtime.h>
#include <hip/hip_bf16.h>
#include <math.h>

#define OBS 512
#define MSG 2048
#define TAU 576
#define TAUP 640      // padded taus row stride
#define QN 16320
#define X2W 16896
#define INW 3136
#define PIW 2560

typedef short short8v __attribute__((ext_vector_type(8)));
typedef float f32x4 __attribute__((ext_vector_type(4)));
typedef __hip_bfloat16 bf;

__device__ inline unsigned short bfbits(float x) {
  bf h = __float2bfloat16(x);
  return *reinterpret_cast<unsigned short*>(&h);
}

__device__ inline ushort4 cvtf4(float4 v) {
  ushort4 r;
  r.x = bfbits(v.x); r.y = bfbits(v.y); r.z = bfbits(v.z); r.w = bfbits(v.w);
  return r;
}

__device__ inline void gload16(const void* g, void* l) {
  __builtin_amdgcn_global_load_lds((__attribute__((address_space(1))) void*)(g),
                                   (__attribute__((address_space(3))) void*)(l), 16, 0, 0);
}

// ---------------- bf16-MFMA NT matmul, BM=BN=64, BK=64, dbuf, 4 waves ----------------
// C[m,n] = act(sum_k A[m,k]*W[n,k] + bias[n]); A bf16 (lda), W fp32 (ldw, cvt in-reg).
// XCD-bijective tile swizzle (T1/m204), m-fastest decomposition: the 4 m-blocks sharing
// one W-strip are contiguous logicals -> same XCD -> W re-read from its L2, not L3/HBM.
// ATOMIC: blockIdx.z = K-chunk, fp32 atomicAdd into bias-prefilled C (no epilogue).
// DUAL: blockIdx.z picks set (GRU gi/gh pair).
struct MMSet {
  const bf* A;
  const float* W;
  const float* bias;
  float* C;
  bf* Cb;
  int lda, ldw, ldc, ldcb;
};

template<int ACT, bool ATOMIC, bool DUAL>
__global__ __launch_bounds__(256)
void k_mm(MMSet s0, MMSet s1, int kSteps)
{
  __shared__ bf As[2][64 * 64];
  __shared__ bf Bs[2][64 * 64];
  const MMSet S = (DUAL && blockIdx.z) ? s1 : s0;
  const int tid = threadIdx.x;
  const int lane = tid & 63;
  const int wid = tid >> 6;

  // XCD-bijective swizzle within the x-y plane; logical ids decompose m-fastest.
  const int gx = gridDim.x, gy = gridDim.y;
  const int nwg = gx * gy;
  const int hw = blockIdx.y * gx + blockIdx.x;
  const int qq = nwg >> 3, rr = nwg & 7;
  const int xcd = hw & 7, idx = hw >> 3;
  const int logical = (xcd < rr) ? xcd * (qq + 1) + idx
                                 : rr * (qq + 1) + (xcd - rr) * qq + idx;
  const int m0 = (logical % gy) * 64;
  const int n0 = (logical / gy) * 64;
  const size_t k0 = ATOMIC ? (size_t)blockIdx.z * kSteps * 64 : 0;

  const bf* Ab = S.A + (size_t)m0 * S.lda + k0;
  const float* Bb = S.W + (size_t)n0 * S.ldw + k0;

  // A staging: 512 chunks of 16B (8 bf16), 2 rounds. LDS linear; global col swizzled.
  int arow[2], acol[2], adst[2];
#pragma unroll
  for (int r = 0; r < 2; ++r) {
    int chunk = r * 256 + tid;
    arow[r] = chunk >> 3;
    acol[r] = ((chunk & 7) ^ (arow[r] & 7)) * 8;
    adst[r] = chunk * 8;
  }
  // W staging: 1024 float4 chunks, 4 rounds; dest = swizzled 8B (4 bf16) slot.
  int brow[4], bcol[4], bdst[4];
#pragma unroll
  for (int r = 0; r < 4; ++r) {
    int c = r * 256 + tid;
    brow[r] = c >> 4;
    int g = (c & 15) >> 1, half = c & 1;
    bcol[r] = (c & 15) * 4;
    bdst[r] = brow[r] * 64 + ((g ^ (brow[r] & 7)) << 3) + half * 4;
  }

  const int wr = wid >> 1, wc = wid & 1;   // wave tile 32m x 32n
  const int fr = lane & 15, q = lane >> 4;
  const int xm = fr & 7;

  f32x4 acc00 = {}, acc01 = {}, acc10 = {}, acc11 = {};
  float4 w0, w1, w2, w3;

  auto stageA = [&](int buf, int kt) {
#pragma unroll
    for (int r = 0; r < 2; ++r)
      gload16(Ab + (size_t)arow[r] * S.lda + kt + acol[r], &As[buf][adst[r]]);
  };
  auto loadB = [&](int kt) {
    w0 = *(const float4*)(Bb + (size_t)brow[0] * S.ldw + kt + bcol[0]);
    w1 = *(const float4*)(Bb + (size_t)brow[1] * S.ldw + kt + bcol[1]);
    w2 = *(const float4*)(Bb + (size_t)brow[2] * S.ldw + kt + bcol[2]);
    w3 = *(const float4*)(Bb + (size_t)brow[3] * S.ldw + kt + bcol[3]);
  };
  auto writeB = [&](int buf) {
    *(ushort4*)&Bs[buf][bdst[0]] = cvtf4(w0);
    *(ushort4*)&Bs[buf][bdst[1]] = cvtf4(w1);
    *(ushort4*)&Bs[buf][bdst[2]] = cvtf4(w2);
    *(ushort4*)&Bs[buf][bdst[3]] = cvtf4(w3);
  };

  stageA(0, 0);
  loadB(0);
  writeB(0);
  __syncthreads();

  for (int t = 0; t < kSteps; ++t) {
    const int buf = t & 1;
    if (t + 1 < kSteps) {
      stageA(buf ^ 1, (t + 1) * 64);   // async -> LDS
      loadB((t + 1) * 64);             // issue-early to regs
    }
    const bf* Ac = As[buf];
    const bf* Bc = Bs[buf];
#pragma unroll
    for (int ks = 0; ks < 2; ++ks) {
      const int cc = ks * 4 + q;
      const int co = ((cc ^ xm) << 3);
      short8v a0 = *(const short8v*)&Ac[(wr * 32 +  0 + fr) * 64 + co];
      short8v a1 = *(const short8v*)&Ac[(wr * 32 + 16 + fr) * 64 + co];
      short8v b0 = *(const short8v*)&Bc[(wc * 32 +  0 + fr) * 64 + co];
      short8v b1 = *(const short8v*)&Bc[(wc * 32 + 16 + fr) * 64 + co];
      acc00 = __builtin_amdgcn_mfma_f32_16x16x32_bf16(a0, b0, acc00, 0, 0, 0);
      acc01 = __builtin_amdgcn_mfma_f32_16x16x32_bf16(a0, b1, acc01, 0, 0, 0);
      acc10 = __builtin_amdgcn_mfma_f32_16x16x32_bf16(a1, b0, acc10, 0, 0, 0);
      acc11 = __builtin_amdgcn_mfma_f32_16x16x32_bf16(a1, b1, acc11, 0, 0, 0);
    }
    if (t + 1 < kSteps) writeB(buf ^ 1);   // cvt + ds_write late
    __syncthreads();
  }

  const int mb0 = m0 + wr * 32 + q * 4;
  const int mb1 = mb0 + 16;
  const int nc0 = n0 + wc * 32 + fr;
  const int nc1 = nc0 + 16;
  if (ATOMIC) {
#pragma unroll
    for (int v = 0; v < 4; ++v) {
      atomicAdd(&S.C[(size_t)(mb0 + v) * S.ldc + nc0], acc00[v]);
      atomicAdd(&S.C[(size_t)(mb0 + v) * S.ldc + nc1], acc01[v]);
      atomicAdd(&S.C[(size_t)(mb1 + v) * S.ldc + nc0], acc10[v]);
      atomicAdd(&S.C[(size_t)(mb1 + v) * S.ldc + nc1], acc11[v]);
    }
  } else {
    const float bb0 = S.bias[nc0], bb1 = S.bias[nc1];
#pragma unroll
    for (int v = 0; v < 4; ++v) {
      float v00 = acc00[v] + bb0, v01 = acc01[v] + bb1;
      float v10 = acc10[v] + bb0, v11 = acc11[v] + bb1;
      if (ACT) { v00 = fmaxf(v00, 0.f); v01 = fmaxf(v01, 0.f);
                 v10 = fmaxf(v10, 0.f); v11 = fmaxf(v11, 0.f); }
      if (S.C) {
        S.C[(size_t)(mb0 + v) * S.ldc + nc0] = v00;
        S.C[(size_t)(mb0 + v) * S.ldc + nc1] = v01;
        S.C[(size_t)(mb1 + v) * S.ldc + nc0] = v10;
        S.C[(size_t)(mb1 + v) * S.ldc + nc1] = v11;
      }
      if (S.Cb) {
        S.Cb[(size_t)(mb0 + v) * S.ldcb + nc0] = __float2bfloat16(v00);
        S.Cb[(size_t)(mb0 + v) * S.ldcb + nc1] = __float2bfloat16(v01);
        S.Cb[(size_t)(mb1 + v) * S.ldcb + nc0] = __float2bfloat16(v10);
        S.Cb[(size_t)(mb1 + v) * S.ldcb + nc1] = __float2bfloat16(v11);
      }
    }
  }
}

// -------- fused init: hidden split + taus slabs + msg cvt + bias prefills ------------
__global__ __launch_bounds__(256)
void k_init(const float* __restrict__ in, const float* __restrict__ hid,
            float* __restrict__ h32a, float* __restrict__ h32o, float* __restrict__ h32p,
            bf* __restrict__ hba, bf* __restrict__ hbo,
            bf* __restrict__ hbp, bf* __restrict__ hbp0,
            bf* __restrict__ taus, bf* __restrict__ msgb,
            const float* __restrict__ fo1b, float* __restrict__ xf0, float* __restrict__ xf1,
            const float* __restrict__ pi1b, float* __restrict__ xp0,
            float* __restrict__ xp1, float* __restrict__ xp2)
{
  const int bx = blockIdx.x;
  if (bx < 3072) {                       // hidden split: 256x3072
    int idx = bx * 256 + threadIdx.x;
    int b = idx / 3072, c = idx % 3072;
    float v = hid[idx];
    bf hb = __float2bfloat16(v);
    int j = c & 1023;
    if (c < 1024)      { h32a[b * 1024 + j] = v; hba[b * 1024 + j] = hb; }
    else if (c < 2048) { h32o[b * 1024 + j] = v; hbo[b * 1024 + j] = hb; }
    else               { h32p[b * 1024 + j] = v; hbp[b * 1024 + j] = hb; hbp0[b * 1024 + j] = hb; }
  } else if (bx < 3072 + 1920) {         // taus slabs: 3*256*TAUP
    int idx = (bx - 3072) * 256 + threadIdx.x;
    int t = idx / (256 * TAUP);
    int r = (idx / TAUP) % 256;
    int c = idx % TAUP;
    float v = 0.f;
    if (t == 0 && c < TAU)
      v = (c < OBS) ? in[(size_t)r * INW + OBS + c]
                    : in[(size_t)r * INW + 2 * OBS + (c - OBS)];
    taus[idx] = __float2bfloat16(v);
  } else if (bx < 3072 + 1920 + 2048) {  // msg cvt: 256x2048
    int idx = (bx - 3072 - 1920) * 256 + threadIdx.x;
    int b = idx >> 11, c = idx & 2047;
    msgb[idx] = __float2bfloat16(in[(size_t)b * INW + 1088 + c]);
  } else if (bx < 3072 + 1920 + 2048 + 1024) {  // fo_fc1 bias prefill (both iters)
    int idx = (bx - 3072 - 1920 - 2048) * 256 + threadIdx.x;
    float v = fo1b[idx & 1023];
    xf0[idx] = v; xf1[idx] = v;
  } else {                               // pi_fc1 bias prefill (3 calls)
    int idx = (bx - 3072 - 1920 - 2048 - 1024) * 256 + threadIdx.x;
    float v = pi1b[idx & 1023];
    xp0[idx] = v; xp1[idx] = v; xp2[idx] = v;
  }
}

// ---------------- GRU elementwise (fp32 math, dual fp32+bf16 out) ----------------
__global__ __launch_bounds__(256)
void k_gru(const float* __restrict__ gi, const float* __restrict__ gh,
           const float* __restrict__ hs, int ldsrc,
           float* __restrict__ hd, int lddst, bf* __restrict__ hb)
{
  int idx = blockIdx.x * 256 + threadIdx.x;     // 256*1024
  int b = idx >> 10, j = idx & 1023;
  float ir = gi[b * 3072 + j];
  float iz = gi[b * 3072 + 1024 + j];
  float in_ = gi[b * 3072 + 2048 + j];
  float hr = gh[b * 3072 + j];
  float hz = gh[b * 3072 + 1024 + j];
  float hn = gh[b * 3072 + 2048 + j];
  float r = 1.f / (1.f + expf(-(ir + hr)));
  float z = 1.f / (1.f + expf(-(iz + hz)));
  float n = tanhf(in_ + r * hn);
  float h = hs[(size_t)b * ldsrc + j];
  float o = (1.f - z) * n + z * h;
  hd[(size_t)b * lddst + j] = o;
  hb[idx] = __float2bfloat16(o);
}

// softmax over 64-wide groups of q (bf16, stride QN), scatter (bf16) into x2
__global__ __launch_bounds__(256)
void k_softmax_scatter(const bf* __restrict__ q, bf* __restrict__ x2)
{
  int wid = blockIdx.x * 4 + (threadIdx.x >> 6);
  int lane = threadIdx.x & 63;
  int b = wid / 255, p = wid % 255;
  float v = __bfloat162float(q[(size_t)b * QN + p * 64 + lane]);
  float m = v;
#pragma unroll
  for (int s = 32; s; s >>= 1) m = fmaxf(m, __shfl_xor(m, s));
  float e = expf(v - m);
  float sum = e;
#pragma unroll
  for (int s = 32; s; s >>= 1) sum += __shfl_xor(sum, s);
  float r = e / sum;
  int flat = p * 16384 + b * 64 + lane;
  int bp = flat / QN;
  int j = flat - bp * QN;
  x2[(size_t)bp * X2W + j] = __float2bfloat16(r);
}

__global__ __launch_bounds__(256)
void k_x2_tail(const bf* __restrict__ taus_t, bf* __restrict__ x2)
{
  int idx = blockIdx.x * 256 + threadIdx.x;   // 256*576
  int b = idx / TAU, c = idx % TAU;
  if (c < 64)
    x2[(size_t)b * X2W + QN + c] = taus_t[(size_t)b * TAUP + OBS + c];
  else
    x2[(size_t)b * X2W + QN + 64 + (c - 64)] = taus_t[(size_t)b * TAUP + (c - 64)];
}

__global__ __launch_bounds__(256)
void k_concat_pi_loop(const bf* __restrict__ taus_t, const bf* __restrict__ msg,
                      bf* __restrict__ piin)
{
  int idx = blockIdx.x * 256 + threadIdx.x;   // 256*2560
  int b = idx / PIW, c = idx % PIW;
  piin[idx] = (c < OBS) ? taus_t[(size_t)b * TAUP + c] : msg[b * MSG + (c - OBS)];
}

__global__ __launch_bounds__(256)
void k_concat_pi_final(const float* __restrict__ in, const float* __restrict__ nm,
                       bf* __restrict__ piin)
{
  int idx = blockIdx.x * 256 + threadIdx.x;
  int b = idx / PIW, c = idx % PIW;
  float v = (c < OBS) ? in[(size_t)b * INW + c] : nm[c - OBS];
  piin[idx] = __float2bfloat16(v);
}

__global__ __launch_bounds__(256)
void k_relu_cvt(const float* __restrict__ s, bf* __restrict__ d)
{
  int idx = blockIdx.x * 256 + threadIdx.x;
  d[idx] = __float2bfloat16(fmaxf(s[idx], 0.f));
}

__global__ __launch_bounds__(64)
void k_vv(const bf* __restrict__ taus, const float* __restrict__ w,
          const float* __restrict__ bias, float* __restrict__ vv)
{
  int row = blockIdx.x;        // 0..767
  int lane = threadIdx.x;
  const bf* tr = taus + (size_t)row * TAUP;
  for (int v = 0; v < 8; ++v) {
    float s = 0.f;
    for (int k = lane; k < TAU; k += 64) s += __bfloat162float(tr[k]) * w[v * TAU + k];
#pragma unroll
    for (int d = 32; d; d >>= 1) s += __shfl_xor(s, d);
    if (lane == 0) vv[row * 8 + v] = s + bias[v];
  }
}

__global__ __launch_bounds__(64)
void k_attn(const float* __restrict__ qv, const float* __restrict__ kk,
            const float* __restrict__ vv, float* __restrict__ nm,
            float* __restrict__ out_q)
{
  int b = blockIdx.x;
  int lane = threadIdx.x;
  const float* qb = qv + (size_t)b * 1024;
  float s[3];
#pragma unroll
  for (int t = 0; t < 3; ++t) {
    const float* kb = kk + (size_t)(t * 256 + b) * 1024;
    float acc = 0.f;
    for (int h = lane; h < 1024; h += 64) acc += qb[h] * kb[h];
#pragma unroll
    for (int d = 32; d; d >>= 1) acc += __shfl_xor(acc, d);
    s[t] = acc * (1.f / 32.f);
  }
  float m = fmaxf(s[0], fmaxf(s[1], s[2]));
  float e0 = expf(s[0] - m), e1 = expf(s[1] - m), e2 = expf(s[2] - m);
  float inv = 1.f / (e0 + e1 + e2);
  float a0 = e0 * inv, a1 = e1 * inv, a2 = e2 * inv;
  if (lane < 8) {
    float v = a0 * vv[(0 * 256 + b) * 8 + lane]
            + a1 * vv[(1 * 256 + b) * 8 + lane]
            + a2 * vv[(2 * 256 + b) * 8 + lane];
    nm[b * 8 + lane] = v;
    out_q[b * 72 + lane] = v;
  }
}

__global__ __launch_bounds__(256)
void k_copy_hout(const float* __restrict__ hfa, const float* __restrict__ hfo,
                 float* __restrict__ hout)
{
  int idx = blockIdx.x * 256 + threadIdx.x;   // 256*2048
  int b = idx / 2048, c = idx % 2048;
  float v = (c < 1024) ? hfa[b * 1024 + c] : hfo[b * 1024 + (c - 1024)];
  hout[(size_t)b * 3072 + c] = v;
}

extern "C" void kernel_launch(void* const* d_in, const int* in_sizes, int n_in,
                              void* d_out_v, int out_size, void* d_ws, size_t ws_size,
                              hipStream_t stream)
{
  const float* inputs   = (const float*)d_in[0];
  const float* hidden   = (const float*)d_in[1];
  const float* pi_fc1_w = (const float*)d_in[2];
  const float* pi_fc1_b = (const float*)d_in[3];
  const float* pi_fc2_w = (const float*)d_in[4];
  const float* pi_fc2_b = (const float*)d_in[5];
  const float* fa_fc1_w = (const float*)d_in[6];
  const float* fa_fc1_b = (const float*)d_in[7];
  const float* fa_fc2_w = (const float*)d_in[8];
  const float* fa_fc2_b = (const float*)d_in[9];
  const float* fo_fc1_w = (const float*)d_in[10];
  const float* fo_fc1_b = (const float*)d_in[11];
  const float* fo_fc2_w = (const float*)d_in[12];
  const float* fo_fc2_b = (const float*)d_in[13];
  const float* am_qs_w  = (const float*)d_in[14];
  const float* am_qs_b  = (const float*)d_in[15];
  const float* am_ks_w  = (const float*)d_in[16];
  const float* am_ks_b  = (const float*)d_in[17];
  const float* am_vs_w  = (const float*)d_in[18];
  const float* am_vs_b  = (const float*)d_in[19];
  const float* pi_wih   = (const float*)d_in[20];
  const float* pi_bih   = (const float*)d_in[21];
  const float* pi_whh   = (const float*)d_in[22];
  const float* pi_bhh   = (const float*)d_in[23];
  const float* fa_wih   = (const float*)d_in[24];
  const float* fa_bih   = (const float*)d_in[25];
  const float* fa_whh   = (const float*)d_in[26];
  const float* fa_bhh   = (const float*)d_in[27];
  const float* fo_wih   = (const float*)d_in[28];
  const float* fo_bih   = (const float*)d_in[29];
  const float* fo_whh   = (const float*)d_in[30];
  const float* fo_bhh   = (const float*)d_in[31];

  float* out = (float*)d_out_v;
  char* p = (char*)d_ws;
  auto alloc = [&](size_t bytes) { void* r = p; p += (bytes + 255) & ~(size_t)255; return r; };

  // bf16 activations
  bf* HFAB = (bf*)alloc((size_t)256 * 1024 * 2);
  bf* HFOB = (bf*)alloc((size_t)256 * 1024 * 2);
  bf* HPIB = (bf*)alloc((size_t)256 * 1024 * 2);
  bf* HPI0B = (bf*)alloc((size_t)256 * 1024 * 2);
  bf* XBUFB = (bf*)alloc((size_t)256 * 1024 * 2);
  bf* TAUSB = (bf*)alloc((size_t)3 * 256 * TAUP * 2);
  bf* X2B  = (bf*)alloc((size_t)256 * X2W * 2);
  bf* PIINB = (bf*)alloc((size_t)256 * PIW * 2);
  bf* MSGB = (bf*)alloc((size_t)256 * MSG * 2);
  bf* QBUFB = (bf*)alloc((size_t)256 * QN * 2);
  // fp32
  float* HFA32 = (float*)alloc((size_t)256 * 1024 * 4);
  float* HFO32 = (float*)alloc((size_t)256 * 1024 * 4);
  float* HPI32 = (float*)alloc((size_t)256 * 1024 * 4);
  float* XF32A = (float*)alloc((size_t)256 * 1024 * 4);
  float* XF32B = (float*)alloc((size_t)256 * 1024 * 4);
  float* XP32A = (float*)alloc((size_t)256 * 1024 * 4);
  float* XP32B = (float*)alloc((size_t)256 * 1024 * 4);
  float* XP32C = (float*)alloc((size_t)256 * 1024 * 4);
  float* GI = (float*)alloc((size_t)256 * 3072 * 4);
  float* GH = (float*)alloc((size_t)256 * 3072 * 4);
  float* QV = (float*)alloc((size_t)256 * 1024 * 4);
  float* KK = (float*)alloc((size_t)768 * 1024 * 4);
  float* VV = (float*)alloc((size_t)768 * 8 * 4);
  float* NM = (float*)alloc((size_t)2048 * 4);

  auto mset = [&](const bf* A, int lda, const float* W, int ldw, const float* bias,
                  float* C, int ldc, bf* Cb, int ldcb) {
    MMSet s; s.A = A; s.W = W; s.bias = bias; s.C = C; s.Cb = Cb;
    s.lda = lda; s.ldw = ldw; s.ldc = ldc; s.ldcb = ldcb; return s;
  };
  auto mm = [&](MMSet a, int M, int N, int K, int act) {
    dim3 g(N / 64, M / 64, 1);
    if (act) k_mm<1, false, false><<<g, 256, 0, stream>>>(a, a, K / 64);
    else     k_mm<0, false, false><<<g, 256, 0, stream>>>(a, a, K / 64);
  };
  auto mmAtomic = [&](const bf* A, int lda, const float* W, int ldw,
                      float* C, int M, int N, int K, int z) {
    MMSet s = mset(A, lda, W, ldw, nullptr, C, N, nullptr, 0);
    dim3 g(N / 64, M / 64, z);
    k_mm<0, true, false><<<g, 256, 0, stream>>>(s, s, K / (64 * z));
  };
  auto mmDual = [&](MMSet a, MMSet b, int N, int K) {
    dim3 g(N / 64, 4, 2);
    k_mm<0, false, true><<<g, 256, 0, stream>>>(a, b, K / 64);
  };

  k_init<<<3072 + 1920 + 2048 + 1024 + 1024, 256, 0, stream>>>(inputs, hidden,
      HFA32, HFO32, HPI32, HFAB, HFOB, HPIB, HPI0B, TAUSB, MSGB,
      fo_fc1_b, XF32A, XF32B, pi_fc1_b, XP32A, XP32B, XP32C);

  for (int t = 0; t < 2; ++t) {
    bf* taus_t = TAUSB + (size_t)t * 256 * TAUP;
    bf* taus_n = TAUSB + (size_t)(t + 1) * 256 * TAUP;
    float* xf32 = t ? XF32B : XF32A;
    float* xp32 = t ? XP32B : XP32A;
    // fa branch
    mm(mset(taus_t, TAUP, fa_fc1_w, 512, fa_fc1_b, nullptr, 0, XBUFB, 1024), 256, 1024, 512, 1);
    mmDual(mset(XBUFB, 1024, fa_wih, 1024, fa_bih, GI, 3072, nullptr, 0),
           mset(HFAB, 1024, fa_whh, 1024, fa_bhh, GH, 3072, nullptr, 0), 3072, 1024);
    k_gru<<<1024, 256, 0, stream>>>(GI, GH, HFA32, 1024, HFA32, 1024, HFAB);
    mm(mset(HFAB, 1024, fa_fc2_w, 1024, fa_fc2_b, nullptr, 0, QBUFB, QN), 256, QN, 1024, 0);
    // x2 = [scrambled softmax | a | o]
    k_x2_tail<<<576, 256, 0, stream>>>(taus_t, X2B);
    k_softmax_scatter<<<16320, 256, 0, stream>>>(QBUFB, X2B);
    // fo branch: z=12 atomic onto bias-prefilled buffer
    mmAtomic(X2B, X2W, fo_fc1_w, X2W, xf32, 256, 1024, X2W, 12);
    k_relu_cvt<<<1024, 256, 0, stream>>>(xf32, XBUFB);
    mmDual(mset(XBUFB, 1024, fo_wih, 1024, fo_bih, GI, 3072, nullptr, 0),
           mset(HFOB, 1024, fo_whh, 1024, fo_bhh, GH, 3072, nullptr, 0), 3072, 1024);
    k_gru<<<1024, 256, 0, stream>>>(GI, GH, HFO32, 1024, HFO32, 1024, HFOB);
    mm(mset(HFOB, 1024, fo_fc2_w, 1024, fo_fc2_b, nullptr, 0, taus_n, TAUP), 256, 512, 1024, 0);
    // pi branch: z=4 atomic onto bias-prefilled buffer
    k_concat_pi_loop<<<2560, 256, 0, stream>>>(taus_t, MSGB, PIINB);
    mmAtomic(PIINB, PIW, pi_fc1_w, PIW, xp32, 256, 1024, PIW, 4);
    k_relu_cvt<<<1024, 256, 0, stream>>>(xp32, XBUFB);
    mmDual(mset(XBUFB, 1024, pi_wih, 1024, pi_bih, GI, 3072, nullptr, 0),
           mset(HPIB, 1024, pi_whh, 1024, pi_bhh, GH, 3072, nullptr, 0), 3072, 1024);
    k_gru<<<1024, 256, 0, stream>>>(GI, GH, HPI32, 1024, HPI32, 1024, HPIB);
    mm(mset(HPIB, 1024, pi_fc2_w, 1024, pi_fc2_b, nullptr, 0, taus_n + OBS, TAUP), 256, 64, 1024, 0);
  }

  // attention
  mm(mset(MSGB, MSG, am_qs_w, MSG, am_qs_b, QV, 1024, nullptr, 0), 256, 1024, 2048, 0);
  mm(mset(TAUSB, TAUP, am_ks_w, TAU, am_ks_b, KK, 1024, nullptr, 0), 768, 1024, TAU, 0);
  k_vv<<<768, 64, 0, stream>>>(TAUSB, am_vs_w, am_vs_b, VV);
  k_attn<<<256, 64, 0, stream>>>(QV, KK, VV, NM, out);

  // final pi with original h_pi0
  k_concat_pi_final<<<2560, 256, 0, stream>>>(inputs, NM, PIINB);
  mmAtomic(PIINB, PIW, pi_fc1_w, PIW, XP32C, 256, 1024, PIW, 4);
  k_relu_cvt<<<1024, 256, 0, stream>>>(XP32C, XBUFB);
  mmDual(mset(XBUFB, 1024, pi_wih, 1024, pi_bih, GI, 3072, nullptr, 0),
         mset(HPI0B, 1024, pi_whh, 1024, pi_bhh, GH, 3072, nullptr, 0), 3072, 1024);
  k_gru<<<1024, 256, 0, stream>>>(GI, GH, hidden + 2048, 3072,
                                  out + 256 * 72 + 2048, 3072, HPIB);
  mm(mset(HPIB, 1024, pi_fc2_w, 1024, pi_fc2_b, out + 8, 72, nullptr, 0), 256, 64, 1024, 0);
  k_copy_hout<<<2048, 256, 0, stream>>>(HFA32, HFO32, out + 256 * 72);
  (void)in_sizes; (void)n_in; (void)out_size; (void)ws_size;
}